// Round 1
// 692.018 us; speedup vs baseline: 1.0428x; 1.0428x over previous
//
#include <hip/hip_runtime.h>

// MLMM electrostatics — 3-phase privatized segment-sum (no global atomics).
// R1/R3: 6.6M device f32 atomics hit fabric atomic-rate limit (~400us floor).
// R4: 3-phase (pair->ws, LDS-privatized segsum, reduce) = 721us.
// R5 (this): P1 is divergent-gather request-bound (HBM 17%, VALU 4.8%):
//   ~7-9 divergent VMEM instrs/pair (q_ml + mu 12B + Q 36B w/ line splits).
//   Fix: prepass packs u-side data into ONE 64B line (q, mu[3], Q[9], trQ)
//   -> 4x dwordx4 on a single line + 1 dword (q_mm) = 5 requests/pair.
//   Also: P3 had a 128-long serial FADD chain at <1 block/CU -> 8 accumulators.

static constexpr float KE_F     = 14.399645351950548f;
static constexpr float CUTOFF_F = 10.0f;

typedef float cf4 __attribute__((ext_vector_type(4)));
typedef int   ci4 __attribute__((ext_vector_type(4)));

#define BPG        128    // blocks per subset-group (phase 2)
#define SUBSETS    4
#define MAX_SUBN   12544  // floats of LDS accumulator (50176 B)
#define P2_THREADS 1024

// ---------------- shared pair math (unpacked fallback) ----------------
__device__ __forceinline__ float pair_energy(
    float di, int ui, int vi,
    const float* __restrict__ vp,   // 3 floats
    const float* __restrict__ op,   // 9 floats
    const float* __restrict__ q_ml,
    const float* __restrict__ q_mm,
    const float* __restrict__ mu,
    const float* __restrict__ Q)
{
    if (di > CUTOFF_F) return 0.0f;
    float chi  = 1.0f / di;
    float chi2 = chi * chi;
    float chi3 = chi2 * chi;
    float chi5 = chi3 * chi2;

    float qu = q_ml[ui];
    float qv = q_mm[vi];

    const float* m = mu + 3 * ui;
    float dot = vp[0]*m[0] + vp[1]*m[1] + vp[2]*m[2];

    const float* qq = Q + 9 * ui;
    float S = op[0]*qq[0] + op[1]*qq[1] + op[2]*qq[2]
            + op[3]*qq[3] + op[4]*qq[4] + op[5]*qq[5]
            + op[6]*qq[6] + op[7]*qq[7] + op[8]*qq[8];
    float dm  = (op[0] + op[4] + op[8]) * (1.0f / 3.0f);
    float trQ = qq[0] + qq[4] + qq[8];

    return KE_F * qv * (qu * chi - chi3 * dot + chi5 * (S - dm * trQ));
}

// ---------------- Phase 0: pack u-side data into one 64B line ----------------
// layout per u (16 floats): w0=(q, mu0, mu1, mu2) w1=(Q0..Q3) w2=(Q4..Q7)
//                           w3=(Q8, trQ, 0, 0)
__global__ __launch_bounds__(256) void pack_u_kernel(
    const float* __restrict__ q_ml,
    const float* __restrict__ mu,
    const float* __restrict__ Q,
    cf4* __restrict__ upk,
    int nml)
{
    int u = blockIdx.x * 256 + threadIdx.x;
    if (u >= nml) return;
    const float* m  = mu + 3 * (size_t)u;
    const float* qq = Q  + 9 * (size_t)u;
    cf4 w0, w1, w2, w3;
    w0.x = q_ml[u]; w0.y = m[0]; w0.z = m[1]; w0.w = m[2];
    w1.x = qq[0]; w1.y = qq[1]; w1.z = qq[2]; w1.w = qq[3];
    w2.x = qq[4]; w2.y = qq[5]; w2.z = qq[6]; w2.w = qq[7];
    w3.x = qq[8]; w3.y = qq[0] + qq[4] + qq[8]; w3.z = 0.0f; w3.w = 0.0f;
    cf4* dst = upk + 4 * (size_t)u;
    dst[0] = w0; dst[1] = w1; dst[2] = w2; dst[3] = w3;
}

__device__ __forceinline__ float pair_energy_packed(
    float di, int ui, int vi,
    const float* __restrict__ vp,
    const float* __restrict__ op,
    const cf4* __restrict__ upk,
    const float* __restrict__ q_mm)
{
    if (di > CUTOFF_F) return 0.0f;
    const cf4* up = upk + 4 * (size_t)ui;
    cf4 w0 = up[0], w1 = up[1], w2 = up[2], w3 = up[3];
    float qv = q_mm[vi];

    float chi  = 1.0f / di;
    float chi2 = chi * chi;
    float chi3 = chi2 * chi;
    float chi5 = chi3 * chi2;

    float dot = vp[0]*w0.y + vp[1]*w0.z + vp[2]*w0.w;
    float S = op[0]*w1.x + op[1]*w1.y + op[2]*w1.z + op[3]*w1.w
            + op[4]*w2.x + op[5]*w2.y + op[6]*w2.z + op[7]*w2.w
            + op[8]*w3.x;
    float dm = (op[0] + op[4] + op[8]) * (1.0f / 3.0f);

    return KE_F * qv * (w0.x * chi - chi3 * dot + chi5 * (S - dm * w3.y));
}

// ---------------- Phase 1 (packed): per-pair E -> ws ----------------
__global__ __launch_bounds__(256) void pair_energy_packed_kernel(
    const cf4*   __restrict__ upk,
    const float* __restrict__ q_mm,
    const float* __restrict__ dist,
    const float* __restrict__ vec,
    const float* __restrict__ outer,
    const int*   __restrict__ idx_u,
    const int*   __restrict__ idx_v,
    float* __restrict__ E_out,
    int n4, int npairs)
{
    int t = blockIdx.x * blockDim.x + threadIdx.x;

    if (t < n4) {
        const cf4* d4  = (const cf4*)dist;
        const ci4* iu4 = (const ci4*)idx_u;
        const ci4* iv4 = (const ci4*)idx_v;
        const cf4* v4  = (const cf4*)vec;
        const cf4* o4  = (const cf4*)outer;

        cf4 d = __builtin_nontemporal_load(d4 + t);
        ci4 u = iu4[t];                       // idx_u reused by phase 2 -> cacheable
        ci4 v = __builtin_nontemporal_load(iv4 + t);

        cf4 vv[3];
        #pragma unroll
        for (int k = 0; k < 3; ++k) vv[k] = __builtin_nontemporal_load(v4 + 3 * t + k);
        cf4 oo[9];
        #pragma unroll
        for (int k = 0; k < 9; ++k) oo[k] = __builtin_nontemporal_load(o4 + 9 * t + k);

        const float* vf = (const float*)vv;
        const float* of = (const float*)oo;
        float dd[4] = {d.x, d.y, d.z, d.w};
        int   uu[4] = {u.x, u.y, u.z, u.w};
        int   wv[4] = {v.x, v.y, v.z, v.w};

        // issue all gathers first (single 64B line per pair + one dword)
        cf4 W0[4], W1[4], W2[4], W3[4];
        float QV[4];
        #pragma unroll
        for (int p = 0; p < 4; ++p) {
            if (dd[p] <= CUTOFF_F) {
                const cf4* up = upk + 4 * (size_t)uu[p];
                W0[p] = up[0]; W1[p] = up[1]; W2[p] = up[2]; W3[p] = up[3];
                QV[p] = q_mm[wv[p]];
            }
        }

        cf4 e;
        #pragma unroll
        for (int p = 0; p < 4; ++p) {
            float ev = 0.0f;
            if (dd[p] <= CUTOFF_F) {
                const float* vp = vf + 3 * p;
                const float* op = of + 9 * p;
                float chi  = 1.0f / dd[p];
                float chi2 = chi * chi;
                float chi3 = chi2 * chi;
                float chi5 = chi3 * chi2;
                float dot = vp[0]*W0[p].y + vp[1]*W0[p].z + vp[2]*W0[p].w;
                float S = op[0]*W1[p].x + op[1]*W1[p].y + op[2]*W1[p].z + op[3]*W1[p].w
                        + op[4]*W2[p].x + op[5]*W2[p].y + op[6]*W2[p].z + op[7]*W2[p].w
                        + op[8]*W3[p].x;
                float dm = (op[0] + op[4] + op[8]) * (1.0f / 3.0f);
                ev = KE_F * QV[p] * (W0[p].x * chi - chi3 * dot + chi5 * (S - dm * W3[p].y));
            }
            ((float*)&e)[p] = ev;
        }
        ((cf4*)E_out)[t] = e;                 // cacheable: phase 2 reads it (L3)
    }

    int tail = npairs - 4 * n4;
    if (blockIdx.x == 0 && (int)threadIdx.x < tail) {
        int i = 4 * n4 + threadIdx.x;
        E_out[i] = pair_energy_packed(dist[i], idx_u[i], idx_v[i],
                                      vec + 3*i, outer + 9*i, upk, q_mm);
    }
}

// ---------------- Phase 1 (unpacked fallback): per-pair E -> ws ----------------
__global__ __launch_bounds__(256) void pair_energy_kernel(
    const float* __restrict__ q_ml,
    const float* __restrict__ q_mm,
    const float* __restrict__ mu,
    const float* __restrict__ Q,
    const float* __restrict__ dist,
    const float* __restrict__ vec,
    const float* __restrict__ outer,
    const int*   __restrict__ idx_u,
    const int*   __restrict__ idx_v,
    float* __restrict__ E_out,
    int n4, int npairs)
{
    int t = blockIdx.x * blockDim.x + threadIdx.x;

    if (t < n4) {
        const cf4* d4  = (const cf4*)dist;
        const ci4* iu4 = (const ci4*)idx_u;
        const ci4* iv4 = (const ci4*)idx_v;
        const cf4* v4  = (const cf4*)vec;
        const cf4* o4  = (const cf4*)outer;

        cf4 d = __builtin_nontemporal_load(d4 + t);
        ci4 u = iu4[t];
        ci4 v = __builtin_nontemporal_load(iv4 + t);

        cf4 vv[3];
        #pragma unroll
        for (int k = 0; k < 3; ++k) vv[k] = __builtin_nontemporal_load(v4 + 3 * t + k);
        cf4 oo[9];
        #pragma unroll
        for (int k = 0; k < 9; ++k) oo[k] = __builtin_nontemporal_load(o4 + 9 * t + k);

        const float* vf = (const float*)vv;
        const float* of = (const float*)oo;
        float dd[4] = {d.x, d.y, d.z, d.w};
        int   uu[4] = {u.x, u.y, u.z, u.w};
        int   wv[4] = {v.x, v.y, v.z, v.w};

        cf4 e;
        #pragma unroll
        for (int p = 0; p < 4; ++p) {
            float ev = pair_energy(dd[p], uu[p], wv[p], vf + 3*p, of + 9*p,
                                   q_ml, q_mm, mu, Q);
            ((float*)&e)[p] = ev;
        }
        ((cf4*)E_out)[t] = e;
    }

    int tail = npairs - 4 * n4;
    if (blockIdx.x == 0 && (int)threadIdx.x < tail) {
        int i = 4 * n4 + threadIdx.x;
        E_out[i] = pair_energy(dist[i], idx_u[i], idx_v[i],
                               vec + 3*i, outer + 9*i, q_ml, q_mm, mu, Q);
    }
}

// ---------------- Phase 2: LDS-privatized segment sum ----------------
__global__ __launch_bounds__(P2_THREADS) void segsum_lds_kernel(
    const int*   __restrict__ idx_u,
    const float* __restrict__ E,
    float* __restrict__ partial,     // [SUBSETS*BPG][subn]
    int n4, int npairs, int subn, int nml)
{
    __shared__ float sacc[MAX_SUBN];

    int s  = blockIdx.x >> 7;        // / BPG
    int b  = blockIdx.x & (BPG - 1);
    int lo = s * subn;
    int hi = lo + subn; if (hi > nml) hi = nml;

    for (int j = threadIdx.x; j < subn; j += P2_THREADS) sacc[j] = 0.0f;
    __syncthreads();

    const ci4* iu4 = (const ci4*)idx_u;
    const cf4* e4  = (const cf4*)E;

    #pragma unroll 2
    for (int t = b * P2_THREADS + threadIdx.x; t < n4; t += BPG * P2_THREADS) {
        ci4 u = iu4[t];
        cf4 e = e4[t];
        if (e.x != 0.0f && u.x >= lo && u.x < hi) atomicAdd(&sacc[u.x - lo], e.x);
        if (e.y != 0.0f && u.y >= lo && u.y < hi) atomicAdd(&sacc[u.y - lo], e.y);
        if (e.z != 0.0f && u.z >= lo && u.z < hi) atomicAdd(&sacc[u.z - lo], e.z);
        if (e.w != 0.0f && u.w >= lo && u.w < hi) atomicAdd(&sacc[u.w - lo], e.w);
    }

    int tail = npairs - 4 * n4;
    if (b == 0 && (int)threadIdx.x < tail) {
        int i  = 4 * n4 + threadIdx.x;
        int ui = idx_u[i];
        float ev = E[i];
        if (ev != 0.0f && ui >= lo && ui < hi) atomicAdd(&sacc[ui - lo], ev);
    }

    __syncthreads();
    float* dst = partial + (size_t)blockIdx.x * subn;
    for (int j = threadIdx.x; j < subn; j += P2_THREADS) dst[j] = sacc[j];
}

// ---------------- Phase 3: reduce partials, add energies ----------------
// R5: 8 independent accumulators — old single-acc version was a 128-long
// serial FADD chain on L3-latency loads at <1 block/CU.
__global__ __launch_bounds__(256) void reduce_partials_kernel(
    const float* __restrict__ energies,
    const float* __restrict__ partial,
    float* __restrict__ out,
    int nml, int subn)
{
    int u = blockIdx.x * 256 + threadIdx.x;
    if (u >= nml) return;
    int s = u / subn;
    int j = u - s * subn;
    const float* p = partial + (size_t)(s * BPG) * subn + j;
    float a0 = 0.0f, a1 = 0.0f, a2 = 0.0f, a3 = 0.0f;
    float a4 = 0.0f, a5 = 0.0f, a6 = 0.0f, a7 = 0.0f;
    #pragma unroll 4
    for (int b = 0; b < BPG; b += 8) {
        a0 += p[(size_t)(b + 0) * subn];
        a1 += p[(size_t)(b + 1) * subn];
        a2 += p[(size_t)(b + 2) * subn];
        a3 += p[(size_t)(b + 3) * subn];
        a4 += p[(size_t)(b + 4) * subn];
        a5 += p[(size_t)(b + 5) * subn];
        a6 += p[(size_t)(b + 6) * subn];
        a7 += p[(size_t)(b + 7) * subn];
    }
    out[u] = energies[u] + (((a0 + a1) + (a2 + a3)) + ((a4 + a5) + (a6 + a7)));
}

// ---------------- Fallback (ws too small): R3 atomic path ----------------
__global__ void init_out_kernel(const float* __restrict__ energies,
                                float* __restrict__ out, int n) {
    int i = blockIdx.x * blockDim.x + threadIdx.x;
    if (i < n) out[i] = energies[i];
}

__global__ __launch_bounds__(256) void mlmm_pair_atomic_kernel(
    const float* __restrict__ q_ml, const float* __restrict__ q_mm,
    const float* __restrict__ mu,   const float* __restrict__ Q,
    const float* __restrict__ dist, const float* __restrict__ vec,
    const float* __restrict__ outer,
    const int* __restrict__ idx_u,  const int* __restrict__ idx_v,
    float* __restrict__ out, int npairs)
{
    int i = blockIdx.x * blockDim.x + threadIdx.x;
    if (i >= npairs) return;
    float ev = pair_energy(dist[i], idx_u[i], idx_v[i],
                           vec + 3*i, outer + 9*i, q_ml, q_mm, mu, Q);
    if (ev != 0.0f) unsafeAtomicAdd(out + idx_u[i], ev);
}

extern "C" void kernel_launch(void* const* d_in, const int* in_sizes, int n_in,
                              void* d_out, int out_size, void* d_ws, size_t ws_size,
                              hipStream_t stream) {
    const float* q_ml   = (const float*)d_in[0];
    const float* q_mm   = (const float*)d_in[1];
    const float* mu     = (const float*)d_in[2];
    const float* Q      = (const float*)d_in[3];
    const float* ene    = (const float*)d_in[4];
    const float* dist   = (const float*)d_in[5];
    const float* vec    = (const float*)d_in[6];
    const float* outer  = (const float*)d_in[7];
    const int*   idx_u  = (const int*)d_in[8];
    const int*   idx_v  = (const int*)d_in[9];
    float* out = (float*)d_out;

    int nml    = in_sizes[4];
    int npairs = in_sizes[5];
    int n4     = npairs >> 2;
    int subn   = (nml + SUBSETS - 1) / SUBSETS;

    size_t e_bytes   = (size_t)npairs * sizeof(float);
    size_t e_aligned = (e_bytes + 255) & ~(size_t)255;
    size_t p_bytes   = (size_t)SUBSETS * BPG * subn * sizeof(float);
    size_t p_aligned = (p_bytes + 255) & ~(size_t)255;
    size_t pk_bytes  = (size_t)nml * 64;     // 16 floats per u, 64B-aligned

    bool use_fast   = (subn <= MAX_SUBN) && (ws_size >= e_aligned + p_bytes);
    bool use_packed = use_fast && (ws_size >= e_aligned + p_aligned + pk_bytes);

    if (use_fast) {
        float* ws_E = (float*)d_ws;
        float* ws_P = (float*)((char*)d_ws + e_aligned);

        int blocks = (n4 + 255) / 256;
        if (blocks < 1) blocks = 1;

        if (use_packed) {
            cf4* ws_K = (cf4*)((char*)d_ws + e_aligned + p_aligned);
            pack_u_kernel<<<(nml + 255) / 256, 256, 0, stream>>>(
                q_ml, mu, Q, ws_K, nml);
            pair_energy_packed_kernel<<<blocks, 256, 0, stream>>>(
                ws_K, q_mm, dist, vec, outer, idx_u, idx_v,
                ws_E, n4, npairs);
        } else {
            pair_energy_kernel<<<blocks, 256, 0, stream>>>(
                q_ml, q_mm, mu, Q, dist, vec, outer, idx_u, idx_v,
                ws_E, n4, npairs);
        }
        segsum_lds_kernel<<<SUBSETS * BPG, P2_THREADS, 0, stream>>>(
            idx_u, ws_E, ws_P, n4, npairs, subn, nml);
        {
            int rblocks = (nml + 255) / 256;
            reduce_partials_kernel<<<rblocks, 256, 0, stream>>>(
                ene, ws_P, out, nml, subn);
        }
    } else {
        int threads = 256;
        init_out_kernel<<<(nml + threads - 1) / threads, threads, 0, stream>>>(ene, out, nml);
        mlmm_pair_atomic_kernel<<<(npairs + threads - 1) / threads, threads, 0, stream>>>(
            q_ml, q_mm, mu, Q, dist, vec, outer, idx_u, idx_v, out, npairs);
    }
}